// Round 1
// baseline (1385.766 us; speedup 1.0000x reference)
//
#include <hip/hip_runtime.h>

#define NN 100000
#define NE 1600000
#define BN_EPS 1e-5f

typedef short bf16x8 __attribute__((ext_vector_type(8)));
typedef float f32x4 __attribute__((ext_vector_type(4)));

__device__ __forceinline__ ushort f2bf(float f) {
  union { float f; unsigned u; } cv;
  cv.f = f;
  unsigned u = cv.u;
  u += 0x7fffu + ((u >> 16) & 1u);
  return (ushort)(u >> 16);
}

// One wave per edge, lane d handles dim d. Coalesced 256B gather of h[src],
// 64 fp32 atomics onto neigh[dst].
__global__ void scatter_kernel(const float* __restrict__ h,
                               const int* __restrict__ src,
                               const int* __restrict__ dst,
                               float* __restrict__ neigh) {
  int tid = blockIdx.x * 256 + threadIdx.x;
  int e = tid >> 6;
  int d = tid & 63;
  int s = src[e];
  int t = dst[e];
  atomicAdd(neigh + t * 64 + d, h[s * 64 + d]);
}

// hn_pre = bf16((1+eps)*h + neigh), vectorized x4.
__global__ void prep_h_kernel(const float4* __restrict__ h4,
                              const float4* __restrict__ n4,
                              const float* __restrict__ eps,
                              ushort* __restrict__ hp) {
  int i = blockIdx.x * 256 + threadIdx.x;
  if (i >= NN * 16) return;
  float s = 1.0f + eps[0];
  float4 hv = h4[i];
  float4 nv = n4[i];
  ushort4 o;
  o.x = f2bf(fmaf(s, hv.x, nv.x));
  o.y = f2bf(fmaf(s, hv.y, nv.y));
  o.z = f2bf(fmaf(s, hv.z, nv.z));
  o.w = f2bf(fmaf(s, hv.w, nv.w));
  ((ushort4*)hp)[i] = o;
}

// 2-layer MLP via mfma_f32_16x16x32_bf16. One wave handles 16 rows x 64 cols.
// STATS mode: accumulate per-column sum/sumsq, atomic at end.
// Apply mode: y = relu(scale*(mlp_out)+shift) + resid, store fp32.
// BF16SRC: rows come from bf16 hn_pre; else fp32 e converted on the fly.
template <bool STATS, bool BF16SRC>
__global__ void mlp_kernel(const float* __restrict__ xf,
                           const ushort* __restrict__ xb,
                           const float* __restrict__ W1,
                           const float* __restrict__ b1,
                           const float* __restrict__ W2,
                           const float* __restrict__ b2,
                           const float* __restrict__ gamma,
                           const float* __restrict__ beta,
                           float* __restrict__ ssum,
                           float* __restrict__ ssq,
                           const float* __restrict__ resid,
                           float* __restrict__ dout,
                           int M) {
  const int tid = threadIdx.x;
  const int lane = tid & 63;
  const int wave = tid >> 6;
  const int m = lane & 15;        // MFMA row (A) / col (B,C)
  const int q = lane >> 4;        // quad index
  const int koff = q * 8;         // k offset within frag

  __shared__ __align__(16) ushort sW1[64 * 72];  // transposed [n][k], stride 72
  __shared__ __align__(16) ushort sW2[64 * 72];
  __shared__ __align__(16) ushort sHid[4][16 * 72];  // per-wave hidden tile

  // Stage W1,W2 -> bf16 transposed LDS (once per block).
  for (int idx = tid; idx < 64 * 16; idx += 256) {
    int k = idx >> 4, g = (idx & 15) * 4;
    float4 w1 = *(const float4*)(W1 + k * 64 + g);
    float4 w2 = *(const float4*)(W2 + k * 64 + g);
    sW1[(g + 0) * 72 + k] = f2bf(w1.x);
    sW1[(g + 1) * 72 + k] = f2bf(w1.y);
    sW1[(g + 2) * 72 + k] = f2bf(w1.z);
    sW1[(g + 3) * 72 + k] = f2bf(w1.w);
    sW2[(g + 0) * 72 + k] = f2bf(w2.x);
    sW2[(g + 1) * 72 + k] = f2bf(w2.y);
    sW2[(g + 2) * 72 + k] = f2bf(w2.z);
    sW2[(g + 3) * 72 + k] = f2bf(w2.w);
  }
  __syncthreads();

  // B-frags for both weight matrices held in registers for the whole kernel.
  bf16x8 w1f[4][2], w2f[4][2];
#pragma unroll
  for (int t = 0; t < 4; ++t) {
#pragma unroll
    for (int s = 0; s < 2; ++s) {
      w1f[t][s] = *(const bf16x8*)(&sW1[(16 * t + m) * 72 + 32 * s + koff]);
      w2f[t][s] = *(const bf16x8*)(&sW2[(16 * t + m) * 72 + 32 * s + koff]);
    }
  }

  float b1c[4], b2c[4], scl[4], sft[4];
  const float Minv = 1.0f / (float)M;
#pragma unroll
  for (int t = 0; t < 4; ++t) {
    int c = 16 * t + m;
    b1c[t] = b1[c];
    b2c[t] = b2[c];
    if constexpr (!STATS) {
      float mean = ssum[c] * Minv;
      float var = ssq[c] * Minv - mean * mean;
      float sc = gamma[c] * rsqrtf(var + BN_EPS);
      scl[t] = sc;
      sft[t] = beta[c] - mean * sc;
    }
  }

  float sacc[4] = {0.f, 0.f, 0.f, 0.f};
  float qacc[4] = {0.f, 0.f, 0.f, 0.f};

  ushort* hw = sHid[wave];
  const int ntiles = M >> 4;
  for (int tile = blockIdx.x * 4 + wave; tile < ntiles; tile += gridDim.x * 4) {
    const int r0 = tile << 4;
    const int rowoff = (r0 + m) * 64;
    bf16x8 a0, a1;
    if constexpr (BF16SRC) {
      a0 = *(const bf16x8*)(xb + rowoff + koff);
      a1 = *(const bf16x8*)(xb + rowoff + 32 + koff);
    } else {
      const float* xp = xf + rowoff + koff;
      float4 p0 = *(const float4*)(xp);
      float4 p1 = *(const float4*)(xp + 4);
      float4 p2 = *(const float4*)(xp + 32);
      float4 p3 = *(const float4*)(xp + 36);
      union { bf16x8 v; ushort s[8]; } u0, u1;
      u0.s[0] = f2bf(p0.x); u0.s[1] = f2bf(p0.y); u0.s[2] = f2bf(p0.z); u0.s[3] = f2bf(p0.w);
      u0.s[4] = f2bf(p1.x); u0.s[5] = f2bf(p1.y); u0.s[6] = f2bf(p1.z); u0.s[7] = f2bf(p1.w);
      u1.s[0] = f2bf(p2.x); u1.s[1] = f2bf(p2.y); u1.s[2] = f2bf(p2.z); u1.s[3] = f2bf(p2.w);
      u1.s[4] = f2bf(p3.x); u1.s[5] = f2bf(p3.y); u1.s[6] = f2bf(p3.z); u1.s[7] = f2bf(p3.w);
      a0 = u0.v;
      a1 = u1.v;
    }

    f32x4 acc[4];
#pragma unroll
    for (int t = 0; t < 4; ++t) acc[t] = (f32x4){0.f, 0.f, 0.f, 0.f};
#pragma unroll
    for (int t = 0; t < 4; ++t) {
      acc[t] = __builtin_amdgcn_mfma_f32_16x16x32_bf16(a0, w1f[t][0], acc[t], 0, 0, 0);
      acc[t] = __builtin_amdgcn_mfma_f32_16x16x32_bf16(a1, w1f[t][1], acc[t], 0, 0, 0);
    }

    // hidden (C-layout) -> relu -> bf16 -> LDS -> reread in A-layout.
#pragma unroll
    for (int t = 0; t < 4; ++t) {
#pragma unroll
      for (int r = 0; r < 4; ++r) {
        float hv = fmaxf(acc[t][r] + b1c[t], 0.f);
        hw[(q * 4 + r) * 72 + 16 * t + m] = f2bf(hv);
      }
    }
    bf16x8 h0 = *(const bf16x8*)(&hw[m * 72 + koff]);
    bf16x8 h1 = *(const bf16x8*)(&hw[m * 72 + 32 + koff]);

    f32x4 out[4];
#pragma unroll
    for (int t = 0; t < 4; ++t) out[t] = (f32x4){0.f, 0.f, 0.f, 0.f};
#pragma unroll
    for (int t = 0; t < 4; ++t) {
      out[t] = __builtin_amdgcn_mfma_f32_16x16x32_bf16(h0, w2f[t][0], out[t], 0, 0, 0);
      out[t] = __builtin_amdgcn_mfma_f32_16x16x32_bf16(h1, w2f[t][1], out[t], 0, 0, 0);
    }

    if constexpr (STATS) {
#pragma unroll
      for (int t = 0; t < 4; ++t) {
#pragma unroll
        for (int r = 0; r < 4; ++r) {
          float v = out[t][r] + b2c[t];
          sacc[t] += v;
          qacc[t] += v * v;
        }
      }
    } else {
#pragma unroll
      for (int t = 0; t < 4; ++t) {
#pragma unroll
        for (int r = 0; r < 4; ++r) {
          float v = out[t][r] + b2c[t];
          float y = fmaxf(fmaf(v, scl[t], sft[t]), 0.f);
          int idx = (r0 + q * 4 + r) * 64 + 16 * t + m;
          dout[idx] = y + resid[idx];
        }
      }
    }
  }

  if constexpr (STATS) {
#pragma unroll
    for (int t = 0; t < 4; ++t) {
      float s_ = sacc[t], q_ = qacc[t];
      s_ += __shfl_xor(s_, 16);
      s_ += __shfl_xor(s_, 32);
      q_ += __shfl_xor(q_, 16);
      q_ += __shfl_xor(q_, 32);
      if (lane < 16) {
        atomicAdd(&ssum[16 * t + lane], s_);
        atomicAdd(&ssq[16 * t + lane], q_);
      }
    }
  }
}

extern "C" void kernel_launch(void* const* d_in, const int* in_sizes, int n_in,
                              void* d_out, int out_size, void* d_ws, size_t ws_size,
                              hipStream_t stream) {
  const float* h   = (const float*)d_in[0];
  const float* e   = (const float*)d_in[1];
  const int*   src = (const int*)d_in[2];
  const int*   dst = (const int*)d_in[3];
  const float* eps = (const float*)d_in[4];
  const float* W1  = (const float*)d_in[5];
  const float* b1  = (const float*)d_in[6];
  const float* W2  = (const float*)d_in[7];
  const float* b2  = (const float*)d_in[8];
  const float* gh  = (const float*)d_in[9];
  const float* bh  = (const float*)d_in[10];
  const float* ge  = (const float*)d_in[11];
  const float* be  = (const float*)d_in[12];

  float* outh = (float*)d_out;                       // [NN,64]
  float* oute = outh + (size_t)NN * 64;              // [NE,64]
  float* stats = (float*)d_ws;                       // 256 floats: sum_h,sq_h,sum_e,sq_e
  ushort* hn_pre = (ushort*)((char*)d_ws + 1024);    // [NN,64] bf16

  // out_h region doubles as the neigh accumulator (consumed by prep before
  // apply_h overwrites it). ws is re-poisoned每call -> memset stats each call.
  hipMemsetAsync(outh, 0, (size_t)NN * 64 * sizeof(float), stream);
  hipMemsetAsync(stats, 0, 256 * sizeof(float), stream);

  scatter_kernel<<<NE * 64 / 256, 256, 0, stream>>>(h, src, dst, outh);
  prep_h_kernel<<<NN * 16 / 256, 256, 0, stream>>>((const float4*)h, (const float4*)outh, eps, hn_pre);

  // stats passes
  mlp_kernel<true, false><<<1024, 256, 0, stream>>>(e, nullptr, W1, b1, W2, b2,
      nullptr, nullptr, stats + 128, stats + 192, nullptr, nullptr, NE);
  mlp_kernel<true, true><<<256, 256, 0, stream>>>(nullptr, hn_pre, W1, b1, W2, b2,
      nullptr, nullptr, stats + 0, stats + 64, nullptr, nullptr, NN);

  // apply passes (recompute MLP, normalize, relu, residual, store)
  mlp_kernel<false, false><<<2048, 256, 0, stream>>>(e, nullptr, W1, b1, W2, b2,
      ge, be, stats + 128, stats + 192, e, oute, NE);
  mlp_kernel<false, true><<<512, 256, 0, stream>>>(nullptr, hn_pre, W1, b1, W2, b2,
      gh, bh, stats + 0, stats + 64, h, outh, NN);
}